// Round 10
// baseline (98.052 us; speedup 1.0000x reference)
//
#include <hip/hip_runtime.h>
#include <math.h>

static constexpr int M = 4096;   // batch rows
static constexpr int C = 512;    // classes
static constexpr int D = 128;    // feature dim
static constexpr float ALPHA = 0.5f;

// ---------------- workspace layout (bytes) ----------------
// label     : int[M]      @ 0       fully written by k_label
// d_pos     : float[M]    @ 16384   plain-stored by unique owner thread
// loss_part : float[M*8]  @ 32768   plain-stored, one slot per (m, c-chunk)
// no zero-init needed anywhere; no atomics on global memory.
static constexpr size_t WS_LABEL = 0;
static constexpr size_t WS_DPOS  = 16384;
static constexpr size_t WS_LPART = 32768;

// ---- kernel 1: per-row argmax of onehot -> label[M] ----
// one wave per row; 4 rows per 256-thread block.
__global__ __launch_bounds__(256) void k_label(
    const float* __restrict__ onehot, int* __restrict__ label)
{
    int gtid = blockIdx.x * 256 + threadIdx.x;
    int row  = gtid >> 6;            // grid = M/4 -> row < M always
    int lane = threadIdx.x & 63;

    const float4* oh = reinterpret_cast<const float4*>(onehot + (size_t)row * C);
    float4 a = oh[lane * 2 + 0];
    float4 b = oh[lane * 2 + 1];
    int lbl = -1;
    if (a.x > 0.5f) lbl = lane * 8 + 0;
    if (a.y > 0.5f) lbl = lane * 8 + 1;
    if (a.z > 0.5f) lbl = lane * 8 + 2;
    if (a.w > 0.5f) lbl = lane * 8 + 3;
    if (b.x > 0.5f) lbl = lane * 8 + 4;
    if (b.y > 0.5f) lbl = lane * 8 + 5;
    if (b.z > 0.5f) lbl = lane * 8 + 6;
    if (b.w > 0.5f) lbl = lane * 8 + 7;
    #pragma unroll
    for (int off = 32; off > 0; off >>= 1)
        lbl = max(lbl, __shfl_xor(lbl, off));
    if (lane == 0) label[row] = lbl;
}

// ---- kernel 2: pipelined {gather-newc for class b} + {L1 tile (mb,cb)} ----
// grid = 512 blocks x 256 threads, 36.5 KB LDS. Schedule:
//   issue chunk0 loads -> prologue (overlaps latency) -> write chunk0,
//   issue chunk1 -> barrier -> compute0 -> barrier -> write chunk1 ->
//   barrier -> compute1 -> epilogue.  No fences, no global atomics.
__global__ __launch_bounds__(256) void k_dist(
    const float* __restrict__ x0, const float* __restrict__ centers,
    const int* __restrict__ label,
    float* __restrict__ d_pos, float* __restrict__ loss_part,
    float* __restrict__ out_nc)
{
    __shared__ float xs[64 * 64];    // 16 KB
    __shared__ float cs[64 * 64];    // 16 KB
    __shared__ int   list[1024];     // 4 KB (prologue member list)
    __shared__ float tmp[128];
    __shared__ int   lcount;

    int tid = threadIdx.x;
    int b   = blockIdx.x;
    int mb  = b & 63, cb = b >> 6;
    int m0  = mb * 64, c0 = cb * 64;

    // ===== issue chunk-0 staging loads (consumed after prologue) =====
    // physical quad Q holds logical quad q = (Q&15) ^ ((row>>2)&7): swizzle
    // applied to the GLOBAL address so LDS writes stay linear (conflict-free).
    float4 rx[4], rc[4];
    #pragma unroll
    for (int kk = 0; kk < 4; ++kk) {
        int Q   = kk * 256 + tid;                // 0..1023
        int row = Q >> 4;
        int q   = (Q & 15) ^ ((row >> 2) & 7);
        rx[kk] = *reinterpret_cast<const float4*>(
            x0      + (size_t)(m0 + row) * D + q * 4);
        rc[kk] = *reinterpret_cast<const float4*>(
            centers + (size_t)(c0 + row) * D + q * 4);
    }

    // ===== prologue: gather center update for class b (overlaps loads) =====
    if (tid == 0) lcount = 0;
    __syncthreads();
    {
        const int4* lab4 = reinterpret_cast<const int4*>(label);
        #pragma unroll
        for (int t = 0; t < 4; ++t) {
            int4 v   = lab4[tid + 256 * t];
            int base = (tid + 256 * t) * 4;
            if (v.x == b) { int k = atomicAdd(&lcount, 1); if (k < 1024) list[k] = base + 0; }
            if (v.y == b) { int k = atomicAdd(&lcount, 1); if (k < 1024) list[k] = base + 1; }
            if (v.z == b) { int k = atomicAdd(&lcount, 1); if (k < 1024) list[k] = base + 2; }
            if (v.w == b) { int k = atomicAdd(&lcount, 1); if (k < 1024) list[k] = base + 3; }
        }
    }
    __syncthreads();
    {
        int n = min(lcount, 1024);
        int d = tid & 127;
        int p = tid >> 7;                  // 0/1: even/odd member indices
        float s = 0.f;
        int i = p;
        for (; i + 6 < n; i += 8) {        // 4 loads in flight per wait
            float a0 = x0[(size_t)list[i + 0] * D + d];
            float a1 = x0[(size_t)list[i + 2] * D + d];
            float a2 = x0[(size_t)list[i + 4] * D + d];
            float a3 = x0[(size_t)list[i + 6] * D + d];
            s += (a0 + a1) + (a2 + a3);
        }
        for (; i < n; i += 2) s += x0[(size_t)list[i] * D + d];
        if (p == 1) tmp[d] = s;
        __syncthreads();
        if (p == 0) {
            s += tmp[d];
            float ctr = centers[b * D + d];
            out_nc[b * D + d] = ctr - ALPHA * ((float)n * ctr - s) / ((float)n + 1.0f);
        }
    }

    // ===== write chunk0 -> LDS; issue chunk1 loads =====
    #pragma unroll
    for (int kk = 0; kk < 4; ++kk) {
        int e = (kk * 256 + tid) * 4;
        *reinterpret_cast<float4*>(xs + e) = rx[kk];   // linear: no conflict
        *reinterpret_cast<float4*>(cs + e) = rc[kk];
    }
    #pragma unroll
    for (int kk = 0; kk < 4; ++kk) {
        int Q   = kk * 256 + tid;
        int row = Q >> 4;
        int q   = (Q & 15) ^ ((row >> 2) & 7);
        rx[kk] = *reinterpret_cast<const float4*>(
            x0      + (size_t)(m0 + row) * D + 64 + q * 4);
        rc[kk] = *reinterpret_cast<const float4*>(
            centers + (size_t)(c0 + row) * D + 64 + q * 4);
    }
    __syncthreads();

    // ===== compute: 4m x 4c per thread over each 64-d chunk =====
    int tx = tid & 15;          // -> 4 c rows
    int ty = tid >> 4;          // -> 4 m rows
    int xk = ty & 7;            // read-swizzle key for x rows
    int ck = tx & 7;            // read-swizzle key for c rows

    float acc[4][4];
    #pragma unroll
    for (int i = 0; i < 4; i++)
        #pragma unroll
        for (int j = 0; j < 4; j++) acc[i][j] = 0.f;

    #pragma unroll 4
    for (int q = 0; q < 16; ++q) {       // chunk 0
        int xo = (q ^ xk) << 2;
        int co = (q ^ ck) << 2;
        float4 xa[4], ca[4];
        #pragma unroll
        for (int i = 0; i < 4; ++i)
            xa[i] = *reinterpret_cast<const float4*>(xs + (ty * 4 + i) * 64 + xo);
        #pragma unroll
        for (int j = 0; j < 4; ++j)
            ca[j] = *reinterpret_cast<const float4*>(cs + (tx * 4 + j) * 64 + co);
        #pragma unroll
        for (int i = 0; i < 4; ++i)
            #pragma unroll
            for (int j = 0; j < 4; ++j) {
                acc[i][j] += fabsf(xa[i].x - ca[j].x);   // v_sub+v_add(|mod|)
                acc[i][j] += fabsf(xa[i].y - ca[j].y);
                acc[i][j] += fabsf(xa[i].z - ca[j].z);
                acc[i][j] += fabsf(xa[i].w - ca[j].w);
            }
    }
    __syncthreads();

    // write chunk1 -> LDS
    #pragma unroll
    for (int kk = 0; kk < 4; ++kk) {
        int e = (kk * 256 + tid) * 4;
        *reinterpret_cast<float4*>(xs + e) = rx[kk];
        *reinterpret_cast<float4*>(cs + e) = rc[kk];
    }
    __syncthreads();

    #pragma unroll 4
    for (int q = 0; q < 16; ++q) {       // chunk 1
        int xo = (q ^ xk) << 2;
        int co = (q ^ ck) << 2;
        float4 xa[4], ca[4];
        #pragma unroll
        for (int i = 0; i < 4; ++i)
            xa[i] = *reinterpret_cast<const float4*>(xs + (ty * 4 + i) * 64 + xo);
        #pragma unroll
        for (int j = 0; j < 4; ++j)
            ca[j] = *reinterpret_cast<const float4*>(cs + (tx * 4 + j) * 64 + co);
        #pragma unroll
        for (int i = 0; i < 4; ++i)
            #pragma unroll
            for (int j = 0; j < 4; ++j) {
                acc[i][j] += fabsf(xa[i].x - ca[j].x);
                acc[i][j] += fabsf(xa[i].y - ca[j].y);
                acc[i][j] += fabsf(xa[i].z - ca[j].z);
                acc[i][j] += fabsf(xa[i].w - ca[j].w);
            }
    }

    // ===== epilogue: d_pos (unique owner) + per-chunk exp-sum partials =====
    int lbls[4];
    #pragma unroll
    for (int i = 0; i < 4; i++) lbls[i] = label[m0 + ty * 4 + i];

    #pragma unroll
    for (int i = 0; i < 4; i++) {
        float ps = 0.f;
        #pragma unroll
        for (int j = 0; j < 4; j++) {
            int cg = c0 + tx * 4 + j;
            float dist = acc[i][j];
            if (cg == lbls[i]) {
                d_pos[m0 + ty * 4 + i] = dist;        // unique writer per m
            } else {
                ps += __expf(-dist);
            }
        }
        #pragma unroll
        for (int off = 8; off > 0; off >>= 1)         // 16-lane tx group
            ps += __shfl_xor(ps, off);
        if (tx == 0)
            loss_part[(size_t)(m0 + ty * 4 + i) * 8 + cb] = ps;
    }
}

// ---- kernel 3: loss[m] = d_pos[m] + log1p(sum of 8 chunk partials) ----
__global__ __launch_bounds__(256) void k_fin(
    const float* __restrict__ d_pos, const float* __restrict__ loss_part,
    float* __restrict__ loss_out)
{
    int m = blockIdx.x * 256 + threadIdx.x;
    if (m >= M) return;
    const float4* p = reinterpret_cast<const float4*>(loss_part + (size_t)m * 8);
    float4 a = p[0], b = p[1];
    float s = (a.x + a.y) + (a.z + a.w) + (b.x + b.y) + (b.z + b.w);
    loss_out[m] = d_pos[m] + log1pf(s);
}

extern "C" void kernel_launch(void* const* d_in, const int* in_sizes, int n_in,
                              void* d_out, int out_size, void* d_ws, size_t ws_size,
                              hipStream_t stream)
{
    const float* x0      = (const float*)d_in[0];   // (M, D)
    const float* onehot  = (const float*)d_in[1];   // (M, C)
    const float* centers = (const float*)d_in[2];   // (C, D)
    float* out = (float*)d_out;                     // [0..M) loss, [M..) new_centers

    char* ws = (char*)d_ws;
    int*   label     = (int*)  (ws + WS_LABEL);
    float* d_pos     = (float*)(ws + WS_DPOS);
    float* loss_part = (float*)(ws + WS_LPART);

    k_label<<<M / 4,   256, 0, stream>>>(onehot, label);
    k_dist <<<512,     256, 0, stream>>>(x0, centers, label,
                                         d_pos, loss_part, out + M);
    k_fin  <<<M / 256, 256, 0, stream>>>(d_pos, loss_part, out);
}

// Round 11
// 90.246 us; speedup vs baseline: 1.0865x; 1.0865x over previous
//
#include <hip/hip_runtime.h>
#include <math.h>

static constexpr int M = 4096;   // batch rows
static constexpr int C = 512;    // classes
static constexpr int D = 128;    // feature dim
static constexpr float ALPHA = 0.5f;

// ---------------- workspace layout (bytes) ----------------
// label     : int[M]      @ 0       fully written by k_label
// d_pos     : float[M]    @ 16384   plain-stored by unique owner thread
// loss_part : float[M*8]  @ 32768   plain-stored, one slot per (m, c-chunk)
// no zero-init, no global atomics, no fences.
static constexpr size_t WS_LABEL = 0;
static constexpr size_t WS_DPOS  = 16384;
static constexpr size_t WS_LPART = 32768;

// ---- kernel 1: per-row argmax of onehot -> label[M] ----
// one wave per row; 4 rows per 256-thread block.
__global__ __launch_bounds__(256) void k_label(
    const float* __restrict__ onehot, int* __restrict__ label)
{
    int gtid = blockIdx.x * 256 + threadIdx.x;
    int row  = gtid >> 6;            // grid = M/4 -> row < M always
    int lane = threadIdx.x & 63;

    const float4* oh = reinterpret_cast<const float4*>(onehot + (size_t)row * C);
    float4 a = oh[lane * 2 + 0];
    float4 b = oh[lane * 2 + 1];
    int lbl = -1;
    if (a.x > 0.5f) lbl = lane * 8 + 0;
    if (a.y > 0.5f) lbl = lane * 8 + 1;
    if (a.z > 0.5f) lbl = lane * 8 + 2;
    if (a.w > 0.5f) lbl = lane * 8 + 3;
    if (b.x > 0.5f) lbl = lane * 8 + 4;
    if (b.y > 0.5f) lbl = lane * 8 + 5;
    if (b.z > 0.5f) lbl = lane * 8 + 6;
    if (b.w > 0.5f) lbl = lane * 8 + 7;
    #pragma unroll
    for (int off = 32; off > 0; off >>= 1)
        lbl = max(lbl, __shfl_xor(lbl, off));
    if (lane == 0) label[row] = lbl;
}

// ---- kernel 2: 32x64 L1-distance tile, grid 1024 (4 blocks/CU, 16 waves/CU)
// LDS 24 KB: xs[32][64-d chunk], cs[64][64-d chunk], swizzled at quad level
// via the GLOBAL source address (linear conflict-free ds_write_b128).
// Per-thread 2m x 4c; c-reads 2-way max, x-reads 2-way max (free per m136).
__global__ __launch_bounds__(256) void k_dist(
    const float* __restrict__ x0, const float* __restrict__ centers,
    const int* __restrict__ label,
    float* __restrict__ d_pos, float* __restrict__ loss_part)
{
    __shared__ float xs[32 * 64];    // 8 KB
    __shared__ float cs[64 * 64];    // 16 KB

    int tid = threadIdx.x;
    int b   = blockIdx.x;
    int mb  = b & 127;          // 128 m tiles of 32 rows
    int cb  = b >> 7;           // 8 c chunks of 64
    int m0  = mb * 32, c0 = cb * 64;
    int tx  = tid & 15;         // -> 4 c rows (proven geometry)
    int ty  = tid >> 4;         // 0..15 -> 2 m rows
    int xk  = (ty >> 1) & 7;    // = (row>>2)&7 for rows ty*2+i, i<2
    int ck  = tx & 7;           // = (row>>2)&7 for rows tx*4+j

    float acc[2][4];
    #pragma unroll
    for (int i = 0; i < 2; i++)
        #pragma unroll
        for (int j = 0; j < 4; j++) acc[i][j] = 0.f;

    for (int dc = 0; dc < 2; ++dc) {
        int d0 = dc * 64;
        __syncthreads();   // protect LDS from previous chunk's readers
        // stage x tile: 512 quads, 2 per thread (pre-swizzled global source)
        #pragma unroll
        for (int kk = 0; kk < 2; ++kk) {
            int Q   = kk * 256 + tid;
            int row = Q >> 4;
            int q   = (Q & 15) ^ ((row >> 2) & 7);
            *reinterpret_cast<float4*>(xs + Q * 4) =
                *reinterpret_cast<const float4*>(x0 + (size_t)(m0 + row) * D + d0 + q * 4);
        }
        // stage c tile: 1024 quads, 4 per thread
        #pragma unroll
        for (int kk = 0; kk < 4; ++kk) {
            int Q   = kk * 256 + tid;
            int row = Q >> 4;
            int q   = (Q & 15) ^ ((row >> 2) & 7);
            *reinterpret_cast<float4*>(cs + Q * 4) =
                *reinterpret_cast<const float4*>(centers + (size_t)(c0 + row) * D + d0 + q * 4);
        }
        __syncthreads();

        #pragma unroll 4
        for (int q = 0; q < 16; ++q) {
            int xo = (q ^ xk) << 2;
            int co = (q ^ ck) << 2;
            float4 xa[2], ca[4];
            #pragma unroll
            for (int i = 0; i < 2; ++i)
                xa[i] = *reinterpret_cast<const float4*>(xs + (ty * 2 + i) * 64 + xo);
            #pragma unroll
            for (int j = 0; j < 4; ++j)
                ca[j] = *reinterpret_cast<const float4*>(cs + (tx * 4 + j) * 64 + co);
            #pragma unroll
            for (int i = 0; i < 2; ++i)
                #pragma unroll
                for (int j = 0; j < 4; ++j) {
                    acc[i][j] += fabsf(xa[i].x - ca[j].x);   // v_sub+v_add(|mod|)
                    acc[i][j] += fabsf(xa[i].y - ca[j].y);
                    acc[i][j] += fabsf(xa[i].z - ca[j].z);
                    acc[i][j] += fabsf(xa[i].w - ca[j].w);
                }
        }
    }

    // epilogue: d_pos (unique owner) + per-chunk exp-sum partials
    int lbls[2];
    #pragma unroll
    for (int i = 0; i < 2; i++) lbls[i] = label[m0 + ty * 2 + i];

    #pragma unroll
    for (int i = 0; i < 2; i++) {
        float ps = 0.f;
        #pragma unroll
        for (int j = 0; j < 4; j++) {
            int cg = c0 + tx * 4 + j;
            float dist = acc[i][j];
            if (cg == lbls[i]) {
                d_pos[m0 + ty * 2 + i] = dist;        // unique writer per m
            } else {
                ps += __expf(-dist);
            }
        }
        #pragma unroll
        for (int off = 8; off > 0; off >>= 1)         // 16-lane tx group
            ps += __shfl_xor(ps, off);
        if (tx == 0)
            loss_part[(size_t)(m0 + ty * 2 + i) * 8 + cb] = ps;
    }
}

// ---- kernel 3: {gather center-update for class b} + {loss rows 8b..8b+7} ----
// grid = 512 blocks x 256 threads. Loss loads issued at entry (hide under the
// label scan); gather is the long pole and runs at 2 blocks/CU concurrency.
__global__ __launch_bounds__(256) void k_fin(
    const float* __restrict__ x0, const float* __restrict__ centers,
    const int* __restrict__ label,
    const float* __restrict__ d_pos, const float* __restrict__ loss_part,
    float* __restrict__ out_nc, float* __restrict__ loss_out)
{
    __shared__ int   list[1024];
    __shared__ float tmp[128];
    __shared__ int   lcount;

    int b   = blockIdx.x;
    int tid = threadIdx.x;

    // issue loss loads early (consumed at the end)
    int   m  = b * 8 + (tid >> 3);           // 8 rows per block
    float lp = 0.f, dp = 0.f;
    if (tid < 64) {
        lp = loss_part[(size_t)m * 8 + (tid & 7)];
        dp = d_pos[m];
    }

    // ----- center update for class b (LDS member list + gather) -----
    if (tid == 0) lcount = 0;
    __syncthreads();
    {
        const int4* lab4 = reinterpret_cast<const int4*>(label);
        #pragma unroll
        for (int t = 0; t < 4; ++t) {
            int4 v   = lab4[tid + 256 * t];
            int base = (tid + 256 * t) * 4;
            if (v.x == b) { int k = atomicAdd(&lcount, 1); if (k < 1024) list[k] = base + 0; }
            if (v.y == b) { int k = atomicAdd(&lcount, 1); if (k < 1024) list[k] = base + 1; }
            if (v.z == b) { int k = atomicAdd(&lcount, 1); if (k < 1024) list[k] = base + 2; }
            if (v.w == b) { int k = atomicAdd(&lcount, 1); if (k < 1024) list[k] = base + 3; }
        }
    }
    __syncthreads();
    {
        int n = min(lcount, 1024);
        int d = tid & 127;
        int p = tid >> 7;                  // 0/1: even/odd member indices
        float s = 0.f;
        int i = p;
        for (; i + 6 < n; i += 8) {        // 4 loads in flight per wait
            float a0 = x0[(size_t)list[i + 0] * D + d];
            float a1 = x0[(size_t)list[i + 2] * D + d];
            float a2 = x0[(size_t)list[i + 4] * D + d];
            float a3 = x0[(size_t)list[i + 6] * D + d];
            s += (a0 + a1) + (a2 + a3);
        }
        for (; i < n; i += 2) s += x0[(size_t)list[i] * D + d];
        if (p == 1) tmp[d] = s;
        __syncthreads();
        if (p == 0) {
            s += tmp[d];
            float ctr = centers[b * D + d];
            out_nc[b * D + d] = ctr - ALPHA * ((float)n * ctr - s) / ((float)n + 1.0f);
        }
    }

    // ----- finalize 8 losses (8-lane groups within wave 0) -----
    if (tid < 64) {
        float s = lp;
        #pragma unroll
        for (int off = 4; off > 0; off >>= 1)
            s += __shfl_xor(s, off);
        if ((tid & 7) == 0)
            loss_out[m] = dp + log1pf(s);
    }
}

extern "C" void kernel_launch(void* const* d_in, const int* in_sizes, int n_in,
                              void* d_out, int out_size, void* d_ws, size_t ws_size,
                              hipStream_t stream)
{
    const float* x0      = (const float*)d_in[0];   // (M, D)
    const float* onehot  = (const float*)d_in[1];   // (M, C)
    const float* centers = (const float*)d_in[2];   // (C, D)
    float* out = (float*)d_out;                     // [0..M) loss, [M..) new_centers

    char* ws = (char*)d_ws;
    int*   label     = (int*)  (ws + WS_LABEL);
    float* d_pos     = (float*)(ws + WS_DPOS);
    float* loss_part = (float*)(ws + WS_LPART);

    k_label<<<M / 4, 256, 0, stream>>>(onehot, label);
    k_dist <<<1024,  256, 0, stream>>>(x0, centers, label, d_pos, loss_part);
    k_fin  <<<C,     256, 0, stream>>>(x0, centers, label, d_pos, loss_part,
                                       out + M, out);
}